// Round 1
// baseline (96.508 us; speedup 1.0000x reference)
//
#include <hip/hip_runtime.h>

// Problem constants
#define TT   512
#define BB   32
#define TS_F 76
#define N_WF 200
#define WF_LEN 1000
#define TEXT_D 200
#define WF_D 100
#define HID  256
#define FC_H 256
#define ROWS (TT*BB)              // 16384
#define KTOT 576                  // padded total feat K (556 -> 576)
#define K1REAL 556

// feat2: ts_out cols [0,256) + spread cols [256,356) + zeros [356,376) + pad
#define FEAT2_LD 384

// ---- fragment-packed B geometry (all pre-split hi/lo, MFMA 16x16x32 layout)
// frag element: frag[l][q] = W^T[tile16*16 + (l&15)][k0 + (l>>4)*8 + q]
// plane = 512 shorts (64 lanes x 8); tile = 2 planes (hi, lo) = 1024 shorts
#define S1_NJ     7                       // 112 cols (100 real)
#define S1_NSTEP  32                      // K = 1024 (1000 real)
#define WWF_STEP  (S1_NJ*1024)            // 7168 shorts per K-step
#define WWF_TOT   (S1_NSTEP*WWF_STEP)     // 229376
#define S2_NSTEP  3                       // K = 96 (76 real)
#define WTS_STEP  (16*1024)               // 16 col-tiles (256 cols)
#define WTS_TOT   (S2_NSTEP*WTS_STEP)     // 49152
#define S4_NCH    18                      // K = 576 (556 real)
#define W1F_STEP  (16*1024)               // 16 col-tiles (256 cols)
#define W1F_TOT   (S4_NCH*W1F_STEP)       // 294912
#define K3_NSTEP  7                       // K = 224 (200 real)
#define K3_NJ     8                       // 128 cols (100 real)
#define WFO3_PER_B (K3_NSTEP*K3_NJ*1024)  // 57344 shorts per batch b
#define WFO3_TOT  (BB*WFO3_PER_B)         // 1835008

typedef __attribute__((ext_vector_type(8))) short short8;
typedef __attribute__((ext_vector_type(4))) short sshort4;
typedef __attribute__((ext_vector_type(4))) float f32x4;

// Truncating bf16 split: hi = v low-16-zeroed (exact subtraction), lo = residual.
__device__ __forceinline__ void split_bf16(float v, short& h, short& l) {
    unsigned u = __builtin_bit_cast(unsigned, v);
    unsigned hu = u & 0xFFFF0000u;
    h = (short)(hu >> 16);
    float r = v - __builtin_bit_cast(float, hu);
    l = (short)(__builtin_bit_cast(unsigned, r) >> 16);
}

// ============ K0: one-time prep ===========================================
// [0,56):    W_wf  -> wwfF fragment pack (split)
// [56,68):   W_ts  -> wtsF fragment pack (split)
// [68,140):  W1    -> w1F  fragment pack (split)
// [140,268): out init (b2)
// [268,396): feat2 zero strip [356,376)
// [396,844): wfo3F zero fill (padding regions must be exact zero for k3)
__global__ __launch_bounds__(256)
void k0_prep(const float* __restrict__ W_wf, const float* __restrict__ W_ts,
             const float* __restrict__ W1, const float* __restrict__ b2,
             short* __restrict__ wwfF, short* __restrict__ wtsF,
             short* __restrict__ w1F, short* __restrict__ wfo3F,
             float* __restrict__ out,
             short* __restrict__ featH, short* __restrict__ featL)
{
    const int b = blockIdx.x, tid = threadIdx.x;
    if (b < 56) {                       // wwf: 32 steps x 7 tiles x 64 lanes
        int idx = b*256 + tid;          // [0,14336)
        int l = idx & 63;
        int t = idx >> 6;               // 0..223
        int jt = t % 7, st = t / 7;
        int lm = l & 15, lq = l >> 4;
        int c = jt*16 + lm;
        short8 h8, l8;
        #pragma unroll
        for (int q = 0; q < 8; q++) {
            int k = st*32 + lq*8 + q;
            float v = (k < WF_LEN && c < WF_D) ? W_wf[k*WF_D + c] : 0.f;
            short h, s; split_bf16(v, h, s); h8[q]=h; l8[q]=s;
        }
        int off = (st*7 + jt)*1024 + l*8;
        *(short8*)(wwfF + off)       = h8;
        *(short8*)(wwfF + off + 512) = l8;
    } else if (b < 68) {                // wts: 3 steps x 16 tiles x 64 lanes
        int idx = (b-56)*256 + tid;     // [0,3072)
        int l = idx & 63, jj = (idx>>6) & 15, st = idx >> 10;
        int c = jj*16 + (l&15), lq = l >> 4;
        short8 h8, l8;
        #pragma unroll
        for (int q = 0; q < 8; q++) {
            int k = st*32 + lq*8 + q;
            float v = (k < TS_F) ? W_ts[k*HID + c] : 0.f;
            short h, s; split_bf16(v, h, s); h8[q]=h; l8[q]=s;
        }
        int off = (st*16 + jj)*1024 + l*8;
        *(short8*)(wtsF + off)       = h8;
        *(short8*)(wtsF + off + 512) = l8;
    } else if (b < 140) {               // w1: 18 chunks x 16 tiles x 64 lanes
        int idx = (b-68)*256 + tid;     // [0,18432)
        int l = idx & 63, jj = (idx>>6) & 15, ch = idx >> 10;
        int n = jj*16 + (l&15), lq = l >> 4;
        short8 h8, l8;
        #pragma unroll
        for (int q = 0; q < 8; q++) {
            int k = ch*32 + lq*8 + q;
            float v = (k < K1REAL) ? W1[k*FC_H + n] : 0.f;
            short h, s; split_bf16(v, h, s); h8[q]=h; l8[q]=s;
        }
        int off = (ch*16 + jj)*1024 + l*8;
        *(short8*)(w1F + off)       = h8;
        *(short8*)(w1F + off + 512) = l8;
    } else if (b < 268) {               // out init
        int idx = (b-140)*256 + tid;
        out[idx] = b2[idx & 1];
    } else if (b < 396) {               // feat2 zero strip [356,376)
        int idx = (b-268)*256 + tid;
        short* base = (idx >> 14) ? featL : featH;
        int r = idx & 16383;
        sshort4 zz = {0, 0, 0, 0};
        #pragma unroll
        for (int q = 0; q < 5; q++)
            *(sshort4*)&base[(long long)r * FEAT2_LD + 356 + q * 4] = zz;
    } else {                            // wfo3F full zero (114688 thr x 16 shorts)
        long long idx = (b-396)*256 + tid;
        short8 z = {0,0,0,0,0,0,0,0};
        *(short8*)(wfo3F + idx*16)     = z;
        *(short8*)(wfo3F + idx*16 + 8) = z;
    }
}

// ============ K1: s1 (z=1, frag-B) + s2 (frag-B) ===========================
// blocks [0,100):     s1  64 rows x 112 cols, full K=1024, A dbuf in LDS,
//                     epilogue writes wf_out^T (+b_wf) in k3 fragment layout
// blocks [100,1124):  s2  feat2[:,0:256) = tanh(ts @ W_ts + b_ts)
__global__ __launch_bounds__(256)
void k1_main(const float* __restrict__ wf, const float* __restrict__ ts,
             const float* __restrict__ b_wf, const float* __restrict__ b_ts,
             const short* __restrict__ wwfF, const short* __restrict__ wtsF,
             short* __restrict__ wfo3F,
             short* __restrict__ featH, short* __restrict__ featL)
{
    __shared__ short smem[8192];     // 16 KB: s1 A dbuf, s2 A single
    const int b = blockIdx.x, tid = threadIdx.x;
    const int wv = tid >> 6, lane = tid & 63;
    const int m16 = lane & 15, quad = lane >> 4;
    const int fsw = (quad ^ ((m16 >> 1) & 3)) * 8;
    const int ar = tid >> 2, ag = tid & 3;
    const int asw = (ag ^ ((ar >> 1) & 3)) * 8;

    if (b < 100) {
        // ---------------- s1 ----------------
        const int row0 = b * 64;
        short* Ah = smem;            // [2][64][32]
        short* Al = smem + 4096;

        f32x4 acc[7];
        #pragma unroll
        for (int j = 0; j < 7; j++) acc[j] = f32x4{0.f, 0.f, 0.f, 0.f};

        float va[8];
        auto loadA = [&](int c) {
            int kk = c * 32 + ag * 8;
            const float* ap = wf + (long long)(row0 + ar) * WF_LEN + kk;
            if (kk + 8 <= WF_LEN) {
                float4 t0 = ((const float4*)ap)[0];
                float4 t1 = ((const float4*)ap)[1];
                va[0]=t0.x; va[1]=t0.y; va[2]=t0.z; va[3]=t0.w;
                va[4]=t1.x; va[5]=t1.y; va[6]=t1.z; va[7]=t1.w;
            } else {
                #pragma unroll
                for (int q = 0; q < 8; q++) va[q] = (kk + q < WF_LEN) ? ap[q] : 0.f;
            }
        };
        auto storeA = [&](int buf) {
            short8 h8, l8;
            #pragma unroll
            for (int q = 0; q < 8; q++) { short h, s; split_bf16(va[q], h, s); h8[q]=h; l8[q]=s; }
            *(short8*)&Ah[buf*2048 + ar*32 + asw] = h8;
            *(short8*)&Al[buf*2048 + ar*32 + asw] = l8;
        };

        loadA(0); storeA(0);
        __syncthreads();

        for (int c = 0; c < S1_NSTEP; ++c) {
            const int buf = c & 1;
            if (c + 1 < S1_NSTEP) loadA(c + 1);

            // B fragments straight to registers (L2-resident, coalesced)
            const short* fb = wwfF + c * WWF_STEP + lane * 8;
            short8 bh[7], bl[7];
            #pragma unroll
            for (int j = 0; j < 7; j++) {
                bh[j] = *(const short8*)(fb + j * 1024);
                bl[j] = *(const short8*)(fb + j * 1024 + 512);
            }
            short8 a_h = *(const short8*)&Ah[buf*2048 + (wv*16 + m16)*32 + fsw];
            short8 a_l = *(const short8*)&Al[buf*2048 + (wv*16 + m16)*32 + fsw];
            #pragma unroll
            for (int j = 0; j < 7; j++) {
                acc[j] = __builtin_amdgcn_mfma_f32_16x16x32_bf16(a_h, bh[j], acc[j], 0, 0, 0);
                acc[j] = __builtin_amdgcn_mfma_f32_16x16x32_bf16(a_h, bl[j], acc[j], 0, 0, 0);
                acc[j] = __builtin_amdgcn_mfma_f32_16x16x32_bf16(a_l, bh[j], acc[j], 0, 0, 0);
            }
            if (c + 1 < S1_NSTEP) {
                storeA(buf ^ 1);
                __syncthreads();
            }
        }

        // epilogue: +b_wf, split, scatter into k3's B-fragment layout
        #pragma unroll
        for (int j = 0; j < 7; j++) {
            int cc = j * 16 + m16;
            if (cc >= WF_D) continue;
            float bw = b_wf[cc];
            #pragma unroll
            for (int rr = 0; rr < 4; rr++) {
                int r = row0 + wv*16 + quad*4 + rr;
                int bb = r / N_WF, n = r - bb * N_WF;
                float v = acc[j][rr] + bw;
                short h, s; split_bf16(v, h, s);
                int st = n >> 5, kk = n & 31;
                long long off = (long long)bb * WFO3_PER_B + st * (K3_NJ*1024)
                              + j * 1024 + ((kk >> 3) * 16 + m16) * 8 + (kk & 7);
                wfo3F[off]       = h;
                wfo3F[off + 512] = s;
            }
        }
    } else {
        // ---------------- s2 ----------------
        const int id2 = b - 100;
        const int bx = id2 & 3, by = id2 >> 2;
        const int row0 = by * 64, col0 = bx * 64;
        short* Ah = smem;            // [64][32]
        short* Al = smem + 2048;

        f32x4 acc[4];
        #pragma unroll
        for (int j = 0; j < 4; j++) acc[j] = f32x4{0.f, 0.f, 0.f, 0.f};

        for (int st = 0; st < S2_NSTEP; ++st) {
            __syncthreads();
            {   // A: 64x32 from ts, split -> LDS (swizzled)
                int kk = st * 32 + ag * 8;
                const float* ap = ts + (long long)(row0 + ar) * TS_F + kk;
                float v[8];
                if (kk + 8 <= TS_F) {
                    float4 t0 = ((const float4*)ap)[0];
                    float4 t1 = ((const float4*)ap)[1];
                    v[0]=t0.x; v[1]=t0.y; v[2]=t0.z; v[3]=t0.w;
                    v[4]=t1.x; v[5]=t1.y; v[6]=t1.z; v[7]=t1.w;
                } else {
                    #pragma unroll
                    for (int q = 0; q < 8; q++) v[q] = (kk + q < TS_F) ? ap[q] : 0.f;
                }
                short8 h8, l8;
                #pragma unroll
                for (int q = 0; q < 8; q++) { short h, s; split_bf16(v[q], h, s); h8[q]=h; l8[q]=s; }
                *(short8*)&Ah[ar*32 + asw] = h8;
                *(short8*)&Al[ar*32 + asw] = l8;
            }
            __syncthreads();

            const short* fb = wtsF + st * WTS_STEP + (bx*4) * 1024 + lane * 8;
            short8 a_h = *(const short8*)&Ah[(wv*16 + m16)*32 + fsw];
            short8 a_l = *(const short8*)&Al[(wv*16 + m16)*32 + fsw];
            #pragma unroll
            for (int j = 0; j < 4; j++) {
                short8 b_h = *(const short8*)(fb + j * 1024);
                short8 b_l = *(const short8*)(fb + j * 1024 + 512);
                acc[j] = __builtin_amdgcn_mfma_f32_16x16x32_bf16(a_h, b_h, acc[j], 0, 0, 0);
                acc[j] = __builtin_amdgcn_mfma_f32_16x16x32_bf16(a_h, b_l, acc[j], 0, 0, 0);
                acc[j] = __builtin_amdgcn_mfma_f32_16x16x32_bf16(a_l, b_h, acc[j], 0, 0, 0);
            }
        }

        #pragma unroll
        for (int j = 0; j < 4; j++) {
            int c = col0 + j * 16 + m16;
            float bv = b_ts[c];
            #pragma unroll
            for (int rr = 0; rr < 4; rr++) {
                int r = row0 + wv*16 + quad*4 + rr;
                float v = tanhf(acc[j][rr] + bv);
                short h, s; split_bf16(v, h, s);
                long long fo = (long long)r * FEAT2_LD + c;
                featH[fo] = h; featL[fo] = s;
            }
        }
    }
}

// ---- K3: feat2[:,256:356) = (wwm[b] @ wf_out[b]) / 200, frag-B ------------
__global__ __launch_bounds__(256)
void k3_s3(const float* __restrict__ wwm, const short* __restrict__ wfo3F,
           short* __restrict__ featH, short* __restrict__ featL)
{
    __shared__ short Ah[2048], Al[2048];

    const int id = blockIdx.x, tid = threadIdx.x;
    const int wv = tid >> 6, lane = tid & 63;
    const int m16 = lane & 15, quad = lane >> 4;
    const int fsw = (quad ^ ((m16 >> 1) & 3)) * 8;
    const int ar = tid >> 2, ag = tid & 3;
    const int asw = (ag ^ ((ar >> 1) & 3)) * 8;

    const int bz = id >> 4, r4 = id & 15, bx = r4 >> 3, by = r4 & 7;
    const float* A = wwm + (long long)bz * TT * N_WF;
    const short* FB = wfo3F + (long long)bz * WFO3_PER_B;
    const long long frow0 = (long long)bz * TT;
    const int row0 = by * 64, col0 = bx * 64;

    f32x4 acc[4];
    #pragma unroll
    for (int j = 0; j < 4; j++) acc[j] = f32x4{0.f, 0.f, 0.f, 0.f};

    for (int st = 0; st < K3_NSTEP; ++st) {
        __syncthreads();
        {   // A: 64x32 from wwm
            int kk = st * 32 + ag * 8;
            const float* ap = A + (long long)(row0 + ar) * N_WF + kk;
            float v[8];
            if (kk + 8 <= N_WF) {
                float4 t0 = ((const float4*)ap)[0];
                float4 t1 = ((const float4*)ap)[1];
                v[0]=t0.x; v[1]=t0.y; v[2]=t0.z; v[3]=t0.w;
                v[4]=t1.x; v[5]=t1.y; v[6]=t1.z; v[7]=t1.w;
            } else {
                #pragma unroll
                for (int q = 0; q < 8; q++) v[q] = (kk + q < N_WF) ? ap[q] : 0.f;
            }
            short8 h8, l8;
            #pragma unroll
            for (int q = 0; q < 8; q++) { short h, s; split_bf16(v[q], h, s); h8[q]=h; l8[q]=s; }
            *(short8*)&Ah[ar*32 + asw] = h8;
            *(short8*)&Al[ar*32 + asw] = l8;
        }
        __syncthreads();

        const short* fb = FB + st * (K3_NJ*1024) + (bx*4) * 1024 + lane * 8;
        short8 a_h = *(const short8*)&Ah[(wv*16 + m16)*32 + fsw];
        short8 a_l = *(const short8*)&Al[(wv*16 + m16)*32 + fsw];
        #pragma unroll
        for (int j = 0; j < 4; j++) {
            short8 b_h = *(const short8*)(fb + j * 1024);
            short8 b_l = *(const short8*)(fb + j * 1024 + 512);
            acc[j] = __builtin_amdgcn_mfma_f32_16x16x32_bf16(a_h, b_h, acc[j], 0, 0, 0);
            acc[j] = __builtin_amdgcn_mfma_f32_16x16x32_bf16(a_h, b_l, acc[j], 0, 0, 0);
            acc[j] = __builtin_amdgcn_mfma_f32_16x16x32_bf16(a_l, b_h, acc[j], 0, 0, 0);
        }
    }

    #pragma unroll
    for (int j = 0; j < 4; j++) {
        int c = col0 + j * 16 + m16;
        if (c >= WF_D) continue;
        #pragma unroll
        for (int rr = 0; rr < 4; rr++) {
            int r = row0 + wv*16 + quad*4 + rr;
            float v = acc[j][rr] * (1.0f / N_WF);
            short h, s; split_bf16(v, h, s);
            long long fo = (frow0 + r) * (long long)FEAT2_LD + HID + c;
            featH[fo] = h; featL[fo] = s;
        }
    }
}

// ====== K4: s4 + head, 512 threads, frag-B (A-only LDS, 16 KB) =============
__global__ __launch_bounds__(512)
void k4_s4head(const float* __restrict__ texts,
               const short* __restrict__ featH, const short* __restrict__ featL,
               const short* __restrict__ w1F,
               const float* __restrict__ b1, const float* __restrict__ W2,
               float* __restrict__ out)
{
    __shared__ short Ah[4096], Al[4096];   // [2][64][32] each

    const int tid = threadIdx.x;
    const int wv = tid >> 6, lane = tid & 63;
    const int m16 = lane & 15, quad = lane >> 4;
    const int row0 = blockIdx.x * 64;

    const int fsw = (quad ^ ((m16 >> 1) & 3)) * 8;

    // A staging (tid < 256)
    const int ar  = tid >> 2;
    const int ag  = tid & 3;
    const int asw = (ag ^ ((ar >> 1) & 3)) * 8;
    const long long gr = row0 + ar;

    f32x4 acc[4][2];
    #pragma unroll
    for (int i = 0; i < 4; i++)
        #pragma unroll
        for (int j = 0; j < 2; j++) acc[i][j] = f32x4{0.f, 0.f, 0.f, 0.f};

    float  va[8];
    short8 fa_h, fa_l;

    auto load_chunk = [&](int c) {
        if (tid < 256) {
            int kc = c * 32 + ag * 8;
            if (kc + 8 <= TEXT_D) {             // texts (200%8==0: never straddles)
                const float4* p = (const float4*)(texts + gr * TEXT_D + kc);
                float4 t0 = p[0], t1 = p[1];
                va[0]=t0.x; va[1]=t0.y; va[2]=t0.z; va[3]=t0.w;
                va[4]=t1.x; va[5]=t1.y; va[6]=t1.z; va[7]=t1.w;
            } else {
                long long o = gr * FEAT2_LD + (kc - TEXT_D);
                fa_h = *(const short8*)(featH + o);
                fa_l = *(const short8*)(featL + o);
            }
        }
    };

    auto store_chunk = [&](int c, int buf) {
        if (tid < 256) {
            int kc = c * 32 + ag * 8;
            short8 h8, l8;
            if (kc + 8 <= TEXT_D) {
                #pragma unroll
                for (int q = 0; q < 8; q++) { short h, s; split_bf16(va[q], h, s); h8[q]=h; l8[q]=s; }
            } else { h8 = fa_h; l8 = fa_l; }
            *(short8*)&Ah[buf*2048 + ar*32 + asw] = h8;
            *(short8*)&Al[buf*2048 + ar*32 + asw] = l8;
        }
    };

    load_chunk(0);
    store_chunk(0, 0);
    __syncthreads();

    for (int c = 0; c < S4_NCH; c++) {
        const int buf = c & 1;
        if (c + 1 < S4_NCH) load_chunk(c + 1);

        short8 a_h[4], a_l[4];
        #pragma unroll
        for (int ri = 0; ri < 4; ri++) {
            a_h[ri] = *(const short8*)&Ah[buf*2048 + (ri*16 + m16)*32 + fsw];
            a_l[ri] = *(const short8*)&Al[buf*2048 + (ri*16 + m16)*32 + fsw];
        }
        #pragma unroll
        for (int ci = 0; ci < 2; ci++) {
            int jj = wv * 2 + ci;
            const short* fb = w1F + (c * 16 + jj) * 1024 + lane * 8;
            short8 b_h = *(const short8*)fb;
            short8 b_l = *(const short8*)(fb + 512);
            #pragma unroll
            for (int ri = 0; ri < 4; ri++) {
                acc[ri][ci] = __builtin_amdgcn_mfma_f32_16x16x32_bf16(a_h[ri], b_h, acc[ri][ci], 0, 0, 0);
                acc[ri][ci] = __builtin_amdgcn_mfma_f32_16x16x32_bf16(a_h[ri], b_l, acc[ri][ci], 0, 0, 0);
                acc[ri][ci] = __builtin_amdgcn_mfma_f32_16x16x32_bf16(a_l[ri], b_h, acc[ri][ci], 0, 0, 0);
            }
        }
        if (c + 1 < S4_NCH) {
            store_chunk(c + 1, buf ^ 1);
            __syncthreads();
        }
    }

    // epilogue: relu + fused head over this wave's 32 cols
    float o0[4][4] = {}, o1[4][4] = {};
    #pragma unroll
    for (int ci = 0; ci < 2; ci++) {
        int C = wv * 32 + ci * 16 + m16;
        float bv  = b1[C];
        float w20 = W2[C * 2 + 0];
        float w21 = W2[C * 2 + 1];
        #pragma unroll
        for (int ri = 0; ri < 4; ri++)
            #pragma unroll
            for (int rr = 0; rr < 4; rr++) {
                float v = fmaxf(acc[ri][ci][rr] + bv, 0.f);
                o0[ri][rr] += v * w20;
                o1[ri][rr] += v * w21;
            }
    }
    #pragma unroll
    for (int ri = 0; ri < 4; ri++)
        #pragma unroll
        for (int rr = 0; rr < 4; rr++) {
            float s0 = o0[ri][rr], s1 = o1[ri][rr];
            #pragma unroll
            for (int mk = 1; mk < 16; mk <<= 1) {
                s0 += __shfl_xor(s0, mk);
                s1 += __shfl_xor(s1, mk);
            }
            if (m16 == 0) {
                int r = row0 + ri * 16 + quad * 4 + rr;
                atomicAdd(&out[r * 2 + 0], s0);
                atomicAdd(&out[r * 2 + 1], s1);
            }
        }
}

extern "C" void kernel_launch(void* const* d_in, const int* in_sizes, int n_in,
                              void* d_out, int out_size, void* d_ws, size_t ws_size,
                              hipStream_t stream)
{
    const float* texts = (const float*)d_in[0];   // (512,32,200)
    const float* ts    = (const float*)d_in[1];   // (512,32,76)
    const float* wf    = (const float*)d_in[2];   // (32,200,1000)
    const float* wwm   = (const float*)d_in[3];   // (32,512,200)
    const float* W_wf  = (const float*)d_in[4];   // (1000,100)
    const float* b_wf  = (const float*)d_in[5];
    const float* W_ts  = (const float*)d_in[6];   // (76,256)
    const float* b_ts  = (const float*)d_in[7];
    const float* W1    = (const float*)d_in[8];   // (556,256)
    const float* b1    = (const float*)d_in[9];
    const float* W2    = (const float*)d_in[10];  // (256,2)
    const float* b2    = (const float*)d_in[11];
    float* out = (float*)d_out;

    // ---- workspace layout (all disjoint, ~30 MB) ----
    short* wwfF  = (short*)d_ws;                       // 229376
    short* wtsF  = wwfF + WWF_TOT;                     // 49152
    short* w1F   = wtsF + WTS_TOT;                     // 294912
    short* wfo3F = w1F + W1F_TOT;                      // 1835008
    short* featH = wfo3F + WFO3_TOT;                   // 16384*384
    short* featL = featH + (long long)ROWS * FEAT2_LD;

    // 0) one-time: B fragment packs + out init + zero fills
    k0_prep<<<844, 256, 0, stream>>>(W_wf, W_ts, W1, b2,
                                     wwfF, wtsF, w1F, wfo3F, out, featH, featL);

    // 1) s1 (full-K, writes wf_out^T frags) + s2 (feat2[:,0:256))
    k1_main<<<1124, 256, 0, stream>>>(wf, ts, b_wf, b_ts,
                                      wwfF, wtsF, wfo3F, featH, featL);

    // 2) s3 spread cols -> feat2[:,256:356)
    k3_s3<<<512, 256, 0, stream>>>(wwm, wfo3F, featH, featL);

    // 3) s4 + head
    k4_s4head<<<ROWS / 64, 512, 0, stream>>>(texts, featH, featL,
                                             w1F, b1, W2, out);
}

// Round 2
// 78.848 us; speedup vs baseline: 1.2240x; 1.2240x over previous
//
#include <hip/hip_runtime.h>

// Problem constants
#define TT   512
#define BB   32
#define TS_F 76
#define N_WF 200
#define WF_LEN 1000
#define TEXT_D 200
#define WF_D 100
#define HID  256
#define FC_H 256
#define ROWS (TT*BB)              // 16384
#define KTOT 576                  // padded total feat K (556 -> 576)
#define K1REAL 556

// feat2: ts_out cols [0,256) + spread cols [256,356) + zeros [356,376) + pad
#define FEAT2_LD 384

// ---- fragment-packed B geometry (all pre-split hi/lo, MFMA 16x16x32 layout)
// frag element: frag[l][q] = W^T[tile16*16 + (l&15)][k0 + (l>>4)*8 + q]
// plane = 512 shorts (64 lanes x 8); tile = 2 planes (hi, lo) = 1024 shorts
#define S1_NJ     7                       // 112 cols (100 real)
#define S1_NSTEP  32                      // K = 1024 (1000 real)
#define WWF_STEP  (S1_NJ*1024)            // 7168 shorts per K-step
#define WWF_TOT   (S1_NSTEP*WWF_STEP)     // 229376
#define S2_NSTEP  3                       // K = 96 (76 real)
#define WTS_STEP  (16*1024)               // 16 col-tiles (256 cols)
#define WTS_TOT   (S2_NSTEP*WTS_STEP)     // 49152
#define S4_NCH    18                      // K = 576 (556 real)
#define W1F_STEP  (16*1024)               // 16 col-tiles (256 cols)
#define W1F_TOT   (S4_NCH*W1F_STEP)       // 294912
#define K3_NSTEP  7                       // K = 224 (200 real)
#define K3_NJ     8                       // 128 cols (100 real)
#define WFO3_PER_B (K3_NSTEP*K3_NJ*1024)  // 57344 shorts per batch b
#define WFO3_TOT  (BB*WFO3_PER_B)         // 1835008

// s1 split-K partials: partT[z][bb][c(112)][n(224)] f32
#define S1_Z      4
#define PART_C    112
#define PART_N    224
#define PART_PER_Z (BB*PART_C*PART_N)     // 802816 f32

typedef __attribute__((ext_vector_type(8))) short short8;
typedef __attribute__((ext_vector_type(4))) short sshort4;
typedef __attribute__((ext_vector_type(4))) float f32x4;

// Truncating bf16 split: hi = v low-16-zeroed (exact subtraction), lo = residual.
__device__ __forceinline__ void split_bf16(float v, short& h, short& l) {
    unsigned u = __builtin_bit_cast(unsigned, v);
    unsigned hu = u & 0xFFFF0000u;
    h = (short)(hu >> 16);
    float r = v - __builtin_bit_cast(float, hu);
    l = (short)(__builtin_bit_cast(unsigned, r) >> 16);
}

// ============ K0: one-time prep ===========================================
// [0,56):    W_wf  -> wwfF fragment pack (split)
// [56,68):   W_ts  -> wtsF fragment pack (split)
// [68,140):  W1    -> w1F  fragment pack (split)
// [140,268): out init (b2)
// [268,396): feat2 zero strip [356,376)
__global__ __launch_bounds__(256)
void k0_prep(const float* __restrict__ W_wf, const float* __restrict__ W_ts,
             const float* __restrict__ W1, const float* __restrict__ b2,
             short* __restrict__ wwfF, short* __restrict__ wtsF,
             short* __restrict__ w1F,
             float* __restrict__ out,
             short* __restrict__ featH, short* __restrict__ featL)
{
    const int b = blockIdx.x, tid = threadIdx.x;
    if (b < 56) {                       // wwf: 32 steps x 7 tiles x 64 lanes
        int idx = b*256 + tid;          // [0,14336)
        int l = idx & 63;
        int t = idx >> 6;               // 0..223
        int jt = t % 7, st = t / 7;
        int lm = l & 15, lq = l >> 4;
        int c = jt*16 + lm;
        short8 h8, l8;
        #pragma unroll
        for (int q = 0; q < 8; q++) {
            int k = st*32 + lq*8 + q;
            float v = (k < WF_LEN && c < WF_D) ? W_wf[k*WF_D + c] : 0.f;
            short h, s; split_bf16(v, h, s); h8[q]=h; l8[q]=s;
        }
        int off = (st*7 + jt)*1024 + l*8;
        *(short8*)(wwfF + off)       = h8;
        *(short8*)(wwfF + off + 512) = l8;
    } else if (b < 68) {                // wts: 3 steps x 16 tiles x 64 lanes
        int idx = (b-56)*256 + tid;     // [0,3072)
        int l = idx & 63, jj = (idx>>6) & 15, st = idx >> 10;
        int c = jj*16 + (l&15), lq = l >> 4;
        short8 h8, l8;
        #pragma unroll
        for (int q = 0; q < 8; q++) {
            int k = st*32 + lq*8 + q;
            float v = (k < TS_F) ? W_ts[k*HID + c] : 0.f;
            short h, s; split_bf16(v, h, s); h8[q]=h; l8[q]=s;
        }
        int off = (st*16 + jj)*1024 + l*8;
        *(short8*)(wtsF + off)       = h8;
        *(short8*)(wtsF + off + 512) = l8;
    } else if (b < 140) {               // w1: 18 chunks x 16 tiles x 64 lanes
        int idx = (b-68)*256 + tid;     // [0,18432)
        int l = idx & 63, jj = (idx>>6) & 15, ch = idx >> 10;
        int n = jj*16 + (l&15), lq = l >> 4;
        short8 h8, l8;
        #pragma unroll
        for (int q = 0; q < 8; q++) {
            int k = ch*32 + lq*8 + q;
            float v = (k < K1REAL) ? W1[k*FC_H + n] : 0.f;
            short h, s; split_bf16(v, h, s); h8[q]=h; l8[q]=s;
        }
        int off = (ch*16 + jj)*1024 + l*8;
        *(short8*)(w1F + off)       = h8;
        *(short8*)(w1F + off + 512) = l8;
    } else if (b < 268) {               // out init
        int idx = (b-140)*256 + tid;
        out[idx] = b2[idx & 1];
    } else {                            // feat2 zero strip [356,376)
        int idx = (b-268)*256 + tid;
        short* base = (idx >> 14) ? featL : featH;
        int r = idx & 16383;
        sshort4 zz = {0, 0, 0, 0};
        #pragma unroll
        for (int q = 0; q < 5; q++)
            *(sshort4*)&base[(long long)r * FEAT2_LD + 356 + q * 4] = zz;
    }
}

// ============ K1: s1 split-K partials (frag-B) + s2 (frag-B) ===============
// blocks [0,400):     s1  64 rows x 112 cols, K-slice of 256 (8 steps),
//                     f32 partials -> partT[z][bb][c][n]
// blocks [400,1424):  s2  feat2[:,0:256) = tanh(ts @ W_ts + b_ts)
__global__ __launch_bounds__(256)
void k1_main(const float* __restrict__ wf, const float* __restrict__ ts,
             const float* __restrict__ b_ts,
             const short* __restrict__ wwfF, const short* __restrict__ wtsF,
             float* __restrict__ partT,
             short* __restrict__ featH, short* __restrict__ featL)
{
    __shared__ short smem[8192];     // 16 KB: s1 A dbuf, s2 A single
    const int b = blockIdx.x, tid = threadIdx.x;
    const int wv = tid >> 6, lane = tid & 63;
    const int m16 = lane & 15, quad = lane >> 4;
    const int fsw = (quad ^ ((m16 >> 1) & 3)) * 8;
    const int ar = tid >> 2, ag = tid & 3;
    const int asw = (ag ^ ((ar >> 1) & 3)) * 8;

    if (b < 400) {
        // ---------------- s1 (split-K z = b/100) ----------------
        const int by = b % 100, z = b / 100;
        const int row0 = by * 64;
        short* Ah = smem;            // [2][64][32]
        short* Al = smem + 4096;

        f32x4 acc[7];
        #pragma unroll
        for (int j = 0; j < 7; j++) acc[j] = f32x4{0.f, 0.f, 0.f, 0.f};

        float va[8];
        auto loadA = [&](int cg) {
            int kk = cg * 32 + ag * 8;
            const float* ap = wf + (long long)(row0 + ar) * WF_LEN + kk;
            if (kk + 8 <= WF_LEN) {
                float4 t0 = ((const float4*)ap)[0];
                float4 t1 = ((const float4*)ap)[1];
                va[0]=t0.x; va[1]=t0.y; va[2]=t0.z; va[3]=t0.w;
                va[4]=t1.x; va[5]=t1.y; va[6]=t1.z; va[7]=t1.w;
            } else {
                #pragma unroll
                for (int q = 0; q < 8; q++) va[q] = (kk + q < WF_LEN) ? ap[q] : 0.f;
            }
        };
        auto storeA = [&](int buf) {
            short8 h8, l8;
            #pragma unroll
            for (int q = 0; q < 8; q++) { short h, s; split_bf16(va[q], h, s); h8[q]=h; l8[q]=s; }
            *(short8*)&Ah[buf*2048 + ar*32 + asw] = h8;
            *(short8*)&Al[buf*2048 + ar*32 + asw] = l8;
        };

        loadA(z * 8); storeA(0);
        __syncthreads();

        for (int cl = 0; cl < 8; ++cl) {
            const int cg = z * 8 + cl;
            const int buf = cl & 1;
            if (cl + 1 < 8) loadA(cg + 1);

            // B fragments straight to registers (L2-resident, coalesced)
            const short* fb = wwfF + cg * WWF_STEP + lane * 8;
            short8 bh[7], bl[7];
            #pragma unroll
            for (int j = 0; j < 7; j++) {
                bh[j] = *(const short8*)(fb + j * 1024);
                bl[j] = *(const short8*)(fb + j * 1024 + 512);
            }
            short8 a_h = *(const short8*)&Ah[buf*2048 + (wv*16 + m16)*32 + fsw];
            short8 a_l = *(const short8*)&Al[buf*2048 + (wv*16 + m16)*32 + fsw];
            #pragma unroll
            for (int j = 0; j < 7; j++) {
                acc[j] = __builtin_amdgcn_mfma_f32_16x16x32_bf16(a_h, bh[j], acc[j], 0, 0, 0);
                acc[j] = __builtin_amdgcn_mfma_f32_16x16x32_bf16(a_h, bl[j], acc[j], 0, 0, 0);
                acc[j] = __builtin_amdgcn_mfma_f32_16x16x32_bf16(a_l, bh[j], acc[j], 0, 0, 0);
            }
            if (cl + 1 < 8) {
                storeA(buf ^ 1);
                __syncthreads();
            }
        }

        // f32 partial store (float4, disjoint per z -> deterministic)
        float* Cb = partT + (long long)z * PART_PER_Z;
        const int r = row0 + wv*16 + quad*4;          // 4-aligned, never crosses bb
        const int bb2 = r / N_WF, n = r - bb2 * N_WF;
        #pragma unroll
        for (int j = 0; j < 7; j++) {
            int cc = j * 16 + m16;
            if (cc >= WF_D) continue;
            float4 t;
            t.x = acc[j][0]; t.y = acc[j][1]; t.z = acc[j][2]; t.w = acc[j][3];
            *(float4*)&Cb[((long long)bb2 * PART_C + cc) * PART_N + n] = t;
        }
    } else {
        // ---------------- s2 ----------------
        const int id2 = b - 400;
        const int bx = id2 & 3, by = id2 >> 2;
        const int row0 = by * 64, col0 = bx * 64;
        short* Ah = smem;            // [64][32]
        short* Al = smem + 2048;

        f32x4 acc[4];
        #pragma unroll
        for (int j = 0; j < 4; j++) acc[j] = f32x4{0.f, 0.f, 0.f, 0.f};

        for (int st = 0; st < S2_NSTEP; ++st) {
            __syncthreads();
            {   // A: 64x32 from ts, split -> LDS (swizzled)
                int kk = st * 32 + ag * 8;
                const float* ap = ts + (long long)(row0 + ar) * TS_F + kk;
                float v[8];
                if (kk + 8 <= TS_F) {
                    float4 t0 = ((const float4*)ap)[0];
                    float4 t1 = ((const float4*)ap)[1];
                    v[0]=t0.x; v[1]=t0.y; v[2]=t0.z; v[3]=t0.w;
                    v[4]=t1.x; v[5]=t1.y; v[6]=t1.z; v[7]=t1.w;
                } else {
                    #pragma unroll
                    for (int q = 0; q < 8; q++) v[q] = (kk + q < TS_F) ? ap[q] : 0.f;
                }
                short8 h8, l8;
                #pragma unroll
                for (int q = 0; q < 8; q++) { short h, s; split_bf16(v[q], h, s); h8[q]=h; l8[q]=s; }
                *(short8*)&Ah[ar*32 + asw] = h8;
                *(short8*)&Al[ar*32 + asw] = l8;
            }
            __syncthreads();

            const short* fb = wtsF + st * WTS_STEP + (bx*4) * 1024 + lane * 8;
            short8 a_h = *(const short8*)&Ah[(wv*16 + m16)*32 + fsw];
            short8 a_l = *(const short8*)&Al[(wv*16 + m16)*32 + fsw];
            #pragma unroll
            for (int j = 0; j < 4; j++) {
                short8 b_h = *(const short8*)(fb + j * 1024);
                short8 b_l = *(const short8*)(fb + j * 1024 + 512);
                acc[j] = __builtin_amdgcn_mfma_f32_16x16x32_bf16(a_h, b_h, acc[j], 0, 0, 0);
                acc[j] = __builtin_amdgcn_mfma_f32_16x16x32_bf16(a_h, b_l, acc[j], 0, 0, 0);
                acc[j] = __builtin_amdgcn_mfma_f32_16x16x32_bf16(a_l, b_h, acc[j], 0, 0, 0);
            }
        }

        #pragma unroll
        for (int j = 0; j < 4; j++) {
            int c = col0 + j * 16 + m16;
            float bv = b_ts[c];
            #pragma unroll
            for (int rr = 0; rr < 4; rr++) {
                int r = row0 + wv*16 + quad*4 + rr;
                float v = tanhf(acc[j][rr] + bv);
                short h, s; split_bf16(v, h, s);
                long long fo = (long long)r * FEAT2_LD + c;
                featH[fo] = h; featL[fo] = s;
            }
        }
    }
}

// ---- K2: reduce 4 z-slices + b_wf, split, write k3 frag layout ------------
// grid 448 = bb(32) x st(7) x half(2); block 256 = j-half(4 waves) x 64 lanes
__global__ __launch_bounds__(256)
void k2_reduce(const float* __restrict__ partT, const float* __restrict__ b_wf,
               short* __restrict__ wfo3F)
{
    const int blk = blockIdx.x, tid = threadIdx.x;
    const int bb = blk / 14, rem = blk % 14;
    const int st = rem >> 1, half = rem & 1;
    const int j = half * 4 + (tid >> 6);
    const int g = tid & 63;
    const int m16 = g & 15, kk8 = g >> 4;
    const int c = j * 16 + m16;
    const int n = st * 32 + kk8 * 8;

    float v[8];
    if (c < WF_D && n < N_WF) {
        float bw = b_wf[c];
        #pragma unroll
        for (int q = 0; q < 8; q++) v[q] = bw;
        #pragma unroll
        for (int z = 0; z < S1_Z; z++) {
            const float* p = partT + (long long)z * PART_PER_Z
                           + ((long long)bb * PART_C + c) * PART_N + n;
            float4 t0 = ((const float4*)p)[0];
            float4 t1 = ((const float4*)p)[1];
            v[0]+=t0.x; v[1]+=t0.y; v[2]+=t0.z; v[3]+=t0.w;
            v[4]+=t1.x; v[5]+=t1.y; v[6]+=t1.z; v[7]+=t1.w;
        }
    } else {
        #pragma unroll
        for (int q = 0; q < 8; q++) v[q] = 0.f;
    }
    short8 h8, l8;
    #pragma unroll
    for (int q = 0; q < 8; q++) { short h, s; split_bf16(v[q], h, s); h8[q]=h; l8[q]=s; }
    long long base = (long long)bb * WFO3_PER_B + st * (K3_NJ*1024) + j * 1024 + g * 8;
    *(short8*)(wfo3F + base)       = h8;
    *(short8*)(wfo3F + base + 512) = l8;
}

// ---- K3: feat2[:,256:356) = (wwm[b] @ wf_out[b]) / 200, frag-B ------------
__global__ __launch_bounds__(256)
void k3_s3(const float* __restrict__ wwm, const short* __restrict__ wfo3F,
           short* __restrict__ featH, short* __restrict__ featL)
{
    __shared__ short Ah[2048], Al[2048];

    const int id = blockIdx.x, tid = threadIdx.x;
    const int wv = tid >> 6, lane = tid & 63;
    const int m16 = lane & 15, quad = lane >> 4;
    const int fsw = (quad ^ ((m16 >> 1) & 3)) * 8;
    const int ar = tid >> 2, ag = tid & 3;
    const int asw = (ag ^ ((ar >> 1) & 3)) * 8;

    const int bz = id >> 4, r4 = id & 15, bx = r4 >> 3, by = r4 & 7;
    const float* A = wwm + (long long)bz * TT * N_WF;
    const short* FB = wfo3F + (long long)bz * WFO3_PER_B;
    const long long frow0 = (long long)bz * TT;
    const int row0 = by * 64, col0 = bx * 64;

    f32x4 acc[4];
    #pragma unroll
    for (int j = 0; j < 4; j++) acc[j] = f32x4{0.f, 0.f, 0.f, 0.f};

    for (int st = 0; st < K3_NSTEP; ++st) {
        __syncthreads();
        {   // A: 64x32 from wwm
            int kk = st * 32 + ag * 8;
            const float* ap = A + (long long)(row0 + ar) * N_WF + kk;
            float v[8];
            if (kk + 8 <= N_WF) {
                float4 t0 = ((const float4*)ap)[0];
                float4 t1 = ((const float4*)ap)[1];
                v[0]=t0.x; v[1]=t0.y; v[2]=t0.z; v[3]=t0.w;
                v[4]=t1.x; v[5]=t1.y; v[6]=t1.z; v[7]=t1.w;
            } else {
                #pragma unroll
                for (int q = 0; q < 8; q++) v[q] = (kk + q < N_WF) ? ap[q] : 0.f;
            }
            short8 h8, l8;
            #pragma unroll
            for (int q = 0; q < 8; q++) { short h, s; split_bf16(v[q], h, s); h8[q]=h; l8[q]=s; }
            *(short8*)&Ah[ar*32 + asw] = h8;
            *(short8*)&Al[ar*32 + asw] = l8;
        }
        __syncthreads();

        const short* fb = FB + st * (K3_NJ*1024) + (bx*4) * 1024 + lane * 8;
        short8 a_h = *(const short8*)&Ah[(wv*16 + m16)*32 + fsw];
        short8 a_l = *(const short8*)&Al[(wv*16 + m16)*32 + fsw];
        #pragma unroll
        for (int j = 0; j < 4; j++) {
            short8 b_h = *(const short8*)(fb + j * 1024);
            short8 b_l = *(const short8*)(fb + j * 1024 + 512);
            acc[j] = __builtin_amdgcn_mfma_f32_16x16x32_bf16(a_h, b_h, acc[j], 0, 0, 0);
            acc[j] = __builtin_amdgcn_mfma_f32_16x16x32_bf16(a_h, b_l, acc[j], 0, 0, 0);
            acc[j] = __builtin_amdgcn_mfma_f32_16x16x32_bf16(a_l, b_h, acc[j], 0, 0, 0);
        }
    }

    #pragma unroll
    for (int j = 0; j < 4; j++) {
        int c = col0 + j * 16 + m16;
        if (c >= WF_D) continue;
        #pragma unroll
        for (int rr = 0; rr < 4; rr++) {
            int r = row0 + wv*16 + quad*4 + rr;
            float v = acc[j][rr] * (1.0f / N_WF);
            short h, s; split_bf16(v, h, s);
            long long fo = (frow0 + r) * (long long)FEAT2_LD + HID + c;
            featH[fo] = h; featL[fo] = s;
        }
    }
}

// ====== K4: s4 + head, 512 threads, frag-B (A-only LDS, 16 KB) =============
__global__ __launch_bounds__(512)
void k4_s4head(const float* __restrict__ texts,
               const short* __restrict__ featH, const short* __restrict__ featL,
               const short* __restrict__ w1F,
               const float* __restrict__ b1, const float* __restrict__ W2,
               float* __restrict__ out)
{
    __shared__ short Ah[4096], Al[4096];   // [2][64][32] each

    const int tid = threadIdx.x;
    const int wv = tid >> 6, lane = tid & 63;
    const int m16 = lane & 15, quad = lane >> 4;
    const int row0 = blockIdx.x * 64;

    const int fsw = (quad ^ ((m16 >> 1) & 3)) * 8;

    // A staging (tid < 256)
    const int ar  = tid >> 2;
    const int ag  = tid & 3;
    const int asw = (ag ^ ((ar >> 1) & 3)) * 8;
    const long long gr = row0 + ar;

    f32x4 acc[4][2];
    #pragma unroll
    for (int i = 0; i < 4; i++)
        #pragma unroll
        for (int j = 0; j < 2; j++) acc[i][j] = f32x4{0.f, 0.f, 0.f, 0.f};

    float  va[8];
    short8 fa_h, fa_l;

    auto load_chunk = [&](int c) {
        if (tid < 256) {
            int kc = c * 32 + ag * 8;
            if (kc + 8 <= TEXT_D) {             // texts (200%8==0: never straddles)
                const float4* p = (const float4*)(texts + gr * TEXT_D + kc);
                float4 t0 = p[0], t1 = p[1];
                va[0]=t0.x; va[1]=t0.y; va[2]=t0.z; va[3]=t0.w;
                va[4]=t1.x; va[5]=t1.y; va[6]=t1.z; va[7]=t1.w;
            } else {
                long long o = gr * FEAT2_LD + (kc - TEXT_D);
                fa_h = *(const short8*)(featH + o);
                fa_l = *(const short8*)(featL + o);
            }
        }
    };

    auto store_chunk = [&](int c, int buf) {
        if (tid < 256) {
            int kc = c * 32 + ag * 8;
            short8 h8, l8;
            if (kc + 8 <= TEXT_D) {
                #pragma unroll
                for (int q = 0; q < 8; q++) { short h, s; split_bf16(va[q], h, s); h8[q]=h; l8[q]=s; }
            } else { h8 = fa_h; l8 = fa_l; }
            *(short8*)&Ah[buf*2048 + ar*32 + asw] = h8;
            *(short8*)&Al[buf*2048 + ar*32 + asw] = l8;
        }
    };

    load_chunk(0);
    store_chunk(0, 0);
    __syncthreads();

    for (int c = 0; c < S4_NCH; c++) {
        const int buf = c & 1;
        if (c + 1 < S4_NCH) load_chunk(c + 1);

        short8 a_h[4], a_l[4];
        #pragma unroll
        for (int ri = 0; ri < 4; ri++) {
            a_h[ri] = *(const short8*)&Ah[buf*2048 + (ri*16 + m16)*32 + fsw];
            a_l[ri] = *(const short8*)&Al[buf*2048 + (ri*16 + m16)*32 + fsw];
        }
        #pragma unroll
        for (int ci = 0; ci < 2; ci++) {
            int jj = wv * 2 + ci;
            const short* fb = w1F + (c * 16 + jj) * 1024 + lane * 8;
            short8 b_h = *(const short8*)fb;
            short8 b_l = *(const short8*)(fb + 512);
            #pragma unroll
            for (int ri = 0; ri < 4; ri++) {
                acc[ri][ci] = __builtin_amdgcn_mfma_f32_16x16x32_bf16(a_h[ri], b_h, acc[ri][ci], 0, 0, 0);
                acc[ri][ci] = __builtin_amdgcn_mfma_f32_16x16x32_bf16(a_h[ri], b_l, acc[ri][ci], 0, 0, 0);
                acc[ri][ci] = __builtin_amdgcn_mfma_f32_16x16x32_bf16(a_l[ri], b_h, acc[ri][ci], 0, 0, 0);
            }
        }
        if (c + 1 < S4_NCH) {
            store_chunk(c + 1, buf ^ 1);
            __syncthreads();
        }
    }

    // epilogue: relu + fused head over this wave's 32 cols
    float o0[4][4] = {}, o1[4][4] = {};
    #pragma unroll
    for (int ci = 0; ci < 2; ci++) {
        int C = wv * 32 + ci * 16 + m16;
        float bv  = b1[C];
        float w20 = W2[C * 2 + 0];
        float w21 = W2[C * 2 + 1];
        #pragma unroll
        for (int ri = 0; ri < 4; ri++)
            #pragma unroll
            for (int rr = 0; rr < 4; rr++) {
                float v = fmaxf(acc[ri][ci][rr] + bv, 0.f);
                o0[ri][rr] += v * w20;
                o1[ri][rr] += v * w21;
            }
    }
    #pragma unroll
    for (int ri = 0; ri < 4; ri++)
        #pragma unroll
        for (int rr = 0; rr < 4; rr++) {
            float s0 = o0[ri][rr], s1 = o1[ri][rr];
            #pragma unroll
            for (int mk = 1; mk < 16; mk <<= 1) {
                s0 += __shfl_xor(s0, mk);
                s1 += __shfl_xor(s1, mk);
            }
            if (m16 == 0) {
                int r = row0 + ri * 16 + quad * 4 + rr;
                atomicAdd(&out[r * 2 + 0], s0);
                atomicAdd(&out[r * 2 + 1], s1);
            }
        }
}

extern "C" void kernel_launch(void* const* d_in, const int* in_sizes, int n_in,
                              void* d_out, int out_size, void* d_ws, size_t ws_size,
                              hipStream_t stream)
{
    const float* texts = (const float*)d_in[0];   // (512,32,200)
    const float* ts    = (const float*)d_in[1];   // (512,32,76)
    const float* wf    = (const float*)d_in[2];   // (32,200,1000)
    const float* wwm   = (const float*)d_in[3];   // (32,512,200)
    const float* W_wf  = (const float*)d_in[4];   // (1000,100)
    const float* b_wf  = (const float*)d_in[5];
    const float* W_ts  = (const float*)d_in[6];   // (76,256)
    const float* b_ts  = (const float*)d_in[7];
    const float* W1    = (const float*)d_in[8];   // (556,256)
    const float* b1    = (const float*)d_in[9];
    const float* W2    = (const float*)d_in[10];  // (256,2)
    const float* b2    = (const float*)d_in[11];
    float* out = (float*)d_out;

    // ---- workspace layout (all disjoint, ~43 MB) ----
    float* partT = (float*)d_ws;                       // 4*802816 f32
    short* wwfF  = (short*)(partT + S1_Z * PART_PER_Z);
    short* wtsF  = wwfF + WWF_TOT;
    short* w1F   = wtsF + WTS_TOT;
    short* wfo3F = w1F + W1F_TOT;
    short* featH = wfo3F + WFO3_TOT;
    short* featL = featH + (long long)ROWS * FEAT2_LD;

    // 0) one-time: B fragment packs + out init + feat2 zero strip
    k0_prep<<<396, 256, 0, stream>>>(W_wf, W_ts, W1, b2,
                                     wwfF, wtsF, w1F, out, featH, featL);

    // 1) s1 split-K partials + s2 (feat2[:,0:256))
    k1_main<<<1424, 256, 0, stream>>>(wf, ts, b_ts, wwfF, wtsF,
                                      partT, featH, featL);

    // 2) reduce z-slices + b_wf -> wf_out^T frag layout
    k2_reduce<<<448, 256, 0, stream>>>(partT, b_wf, wfo3F);

    // 3) s3 spread cols -> feat2[:,256:356)
    k3_s3<<<512, 256, 0, stream>>>(wwm, wfo3F, featH, featL);

    // 4) s4 + head
    k4_s4head<<<ROWS / 64, 512, 0, stream>>>(texts, featH, featL,
                                             w1F, b1, W2, out);
}

// Round 3
// 76.199 us; speedup vs baseline: 1.2665x; 1.0348x over previous
//
#include <hip/hip_runtime.h>

// Problem constants
#define TT   512
#define BB   32
#define TS_F 76
#define N_WF 200
#define WF_LEN 1000
#define TEXT_D 200
#define WF_D 100
#define HID  256
#define FC_H 256
#define ROWS (TT*BB)              // 16384
#define K1REAL 556

// K-order for s4 (we control W1 packing, so K may be permuted/padded):
// [0,200) texts | [200,224) zeros | [224,608) feat2 (fc = k-224)
// feat2: ts_out fc [0,256) + spread fc [256,356) + zeros [356,384)
#define K4_NCH 19                 // 608 / 32

// ---- fragment-packed B geometry (all pre-split hi/lo, MFMA 16x16x32 layout)
// frag element: frag[l][q] = W^T[tile16*16 + (l&15)][k0 + (l>>4)*8 + q]
// plane = 512 shorts (64 lanes x 8); tile = 2 planes (hi, lo) = 1024 shorts
#define S1_NJ     7                       // 112 cols (100 real)
#define WWF_STEP  (S1_NJ*1024)            // 7168 shorts per K-step
#define WWF_TOT   (32*WWF_STEP)           // 229376
#define S2_NSTEP  3                       // K = 96 (76 real)
#define WTS_STEP  (16*1024)               // 16 col-tiles (256 cols)
#define WTS_TOT   (S2_NSTEP*WTS_STEP)     // 49152
#define W1F_STEP  (16*1024)               // 16 col-tiles (256 cols)
#define W1F_TOT   (K4_NCH*W1F_STEP)       // 311296
#define K3_NSTEP  7                       // K = 224 (200 real)
#define K3_NJ     8                       // 128 cols (100 real)
#define WFO3_PER_B (K3_NSTEP*K3_NJ*1024)  // 57344 shorts per batch b
#define WFO3_TOT  (BB*WFO3_PER_B)         // 1835008

// featA: A-fragment-layout feature planes [rt 256][cf 12][ri 4][lane 64][q 8]
#define FA_TOT    (256LL*12*4*512)        // 6291456 shorts per plane

// s1 split-K partials: partT[z][bb][c(112)][n(224)] f32
#define S1_Z      4
#define PART_C    112
#define PART_N    224
#define PART_PER_Z (BB*PART_C*PART_N)     // 802816 f32

typedef __attribute__((ext_vector_type(8))) short short8;
typedef __attribute__((ext_vector_type(4))) short sshort4;
typedef __attribute__((ext_vector_type(4))) float f32x4;

// Truncating bf16 split: hi = v low-16-zeroed (exact subtraction), lo = residual.
__device__ __forceinline__ void split_bf16(float v, short& h, short& l) {
    unsigned u = __builtin_bit_cast(unsigned, v);
    unsigned hu = u & 0xFFFF0000u;
    h = (short)(hu >> 16);
    float r = v - __builtin_bit_cast(float, hu);
    l = (short)(__builtin_bit_cast(unsigned, r) >> 16);
}

// featA scatter address for feature col fc (0..383), global row r (0..16383)
__device__ __forceinline__ long long fa_addr(int r, int fc) {
    int rt = r >> 6, ri = (r >> 4) & 3, lrow = r & 15;
    int cf = fc >> 5, cg = (fc >> 3) & 3, q = fc & 7;
    return ((((long long)rt * 12 + cf) * 4 + ri) << 9) + ((lrow + cg * 16) << 3) + q;
}

// ============ K0: one-time prep ===========================================
// [0,56):    W_wf -> wwfF fragment pack (split)
// [56,68):   W_ts -> wtsF fragment pack (split)
// [68,144):  W1   -> w1F fragment pack (K-order permuted, split)
// [144,272): out init (b2)
// [272,336): featA zero region fc [356,384)
__global__ __launch_bounds__(256)
void k0_prep(const float* __restrict__ W_wf, const float* __restrict__ W_ts,
             const float* __restrict__ W1, const float* __restrict__ b2,
             short* __restrict__ wwfF, short* __restrict__ wtsF,
             short* __restrict__ w1F,
             float* __restrict__ out,
             short* __restrict__ featAH, short* __restrict__ featAL)
{
    const int b = blockIdx.x, tid = threadIdx.x;
    if (b < 56) {                       // wwf: 32 steps x 7 tiles x 64 lanes
        int idx = b*256 + tid;          // [0,14336)
        int l = idx & 63;
        int t = idx >> 6;               // 0..223
        int jt = t % 7, st = t / 7;
        int c = jt*16 + (l & 15), lq = l >> 4;
        short8 h8, l8;
        #pragma unroll
        for (int q = 0; q < 8; q++) {
            int k = st*32 + lq*8 + q;
            float v = (k < WF_LEN && c < WF_D) ? W_wf[k*WF_D + c] : 0.f;
            short h, s; split_bf16(v, h, s); h8[q]=h; l8[q]=s;
        }
        int off = (st*7 + jt)*1024 + l*8;
        *(short8*)(wwfF + off)       = h8;
        *(short8*)(wwfF + off + 512) = l8;
    } else if (b < 68) {                // wts: 3 steps x 16 tiles x 64 lanes
        int idx = (b-56)*256 + tid;     // [0,3072)
        int l = idx & 63, jj = (idx>>6) & 15, st = idx >> 10;
        int c = jj*16 + (l&15), lq = l >> 4;
        short8 h8, l8;
        #pragma unroll
        for (int q = 0; q < 8; q++) {
            int k = st*32 + lq*8 + q;
            float v = (k < TS_F) ? W_ts[k*HID + c] : 0.f;
            short h, s; split_bf16(v, h, s); h8[q]=h; l8[q]=s;
        }
        int off = (st*16 + jj)*1024 + l*8;
        *(short8*)(wtsF + off)       = h8;
        *(short8*)(wtsF + off + 512) = l8;
    } else if (b < 144) {               // w1: 19 chunks x 16 tiles x 64 lanes
        int idx = (b-68)*256 + tid;     // [0,19456)
        if (idx < K4_NCH*16*64) {
            int l = idx & 63, t = idx >> 6;
            int jj = t & 15, ch = t >> 4;
            int n = jj*16 + (l&15), lq = l >> 4;
            short8 h8, l8;
            #pragma unroll
            for (int q = 0; q < 8; q++) {
                int k = ch*32 + lq*8 + q;    // K-order index [0,608)
                float v = 0.f;
                if (k < 200)                  v = W1[k*FC_H + n];
                else if (k >= 224 && k < 580) v = W1[(k-24)*FC_H + n];
                short h, s; split_bf16(v, h, s); h8[q]=h; l8[q]=s;
            }
            int off = (ch*16 + jj)*1024 + l*8;
            *(short8*)(w1F + off)       = h8;
            *(short8*)(w1F + off + 512) = l8;
        }
    } else if (b < 272) {               // out init
        int idx = (b-144)*256 + tid;
        out[idx] = b2[idx & 1];
    } else {                            // featA zeros fc [356,384): cf=11
        int idx = (b-272)*256 + tid;    // [0,16384) = rt*ri*m16
        int rt = idx >> 6, ri = (idx >> 4) & 3, m = idx & 15;
        long long base = ((((long long)rt*12 + 11)*4 + ri) << 9);
        sshort4 z4 = {0,0,0,0};
        short8 z8 = {0,0,0,0,0,0,0,0};
        *(sshort4*)(featAH + base + m*8 + 4) = z4;   // cg0 q4..7 (fc 356..359)
        *(sshort4*)(featAL + base + m*8 + 4) = z4;
        #pragma unroll
        for (int cg = 1; cg < 4; cg++) {             // fc 360..383
            *(short8*)(featAH + base + (m + cg*16)*8) = z8;
            *(short8*)(featAL + base + (m + cg*16)*8) = z8;
        }
    }
}

// ============ K1: s1 split-K partials (frag-B) + s2 (frag-B) ===============
// blocks [0,400):     s1  64 rows x 112 cols, K-slice of 256 (8 steps),
//                     f32 partials -> partT[z][bb][c][n]
// blocks [400,1424):  s2  featA fc[0,256) = tanh(ts @ W_ts + b_ts)
__global__ __launch_bounds__(256)
void k1_main(const float* __restrict__ wf, const float* __restrict__ ts,
             const float* __restrict__ b_ts,
             const short* __restrict__ wwfF, const short* __restrict__ wtsF,
             float* __restrict__ partT,
             short* __restrict__ featAH, short* __restrict__ featAL)
{
    __shared__ short smem[8192];     // 16 KB: s1 A dbuf, s2 A single
    const int b = blockIdx.x, tid = threadIdx.x;
    const int wv = tid >> 6, lane = tid & 63;
    const int m16 = lane & 15, quad = lane >> 4;
    const int fsw = (quad ^ ((m16 >> 1) & 3)) * 8;
    const int ar = tid >> 2, ag = tid & 3;
    const int asw = (ag ^ ((ar >> 1) & 3)) * 8;

    if (b < 400) {
        // ---------------- s1 (split-K z = b/100) ----------------
        const int by = b % 100, z = b / 100;
        const int row0 = by * 64;
        short* Ah = smem;            // [2][64][32]
        short* Al = smem + 4096;

        f32x4 acc[7];
        #pragma unroll
        for (int j = 0; j < 7; j++) acc[j] = f32x4{0.f, 0.f, 0.f, 0.f};

        float va[8];
        auto loadA = [&](int cg2) {
            int kk = cg2 * 32 + ag * 8;
            const float* ap = wf + (long long)(row0 + ar) * WF_LEN + kk;
            if (kk + 8 <= WF_LEN) {
                float4 t0 = ((const float4*)ap)[0];
                float4 t1 = ((const float4*)ap)[1];
                va[0]=t0.x; va[1]=t0.y; va[2]=t0.z; va[3]=t0.w;
                va[4]=t1.x; va[5]=t1.y; va[6]=t1.z; va[7]=t1.w;
            } else {
                #pragma unroll
                for (int q = 0; q < 8; q++) va[q] = (kk + q < WF_LEN) ? ap[q] : 0.f;
            }
        };
        auto storeA = [&](int buf) {
            short8 h8, l8;
            #pragma unroll
            for (int q = 0; q < 8; q++) { short h, s; split_bf16(va[q], h, s); h8[q]=h; l8[q]=s; }
            *(short8*)&Ah[buf*2048 + ar*32 + asw] = h8;
            *(short8*)&Al[buf*2048 + ar*32 + asw] = l8;
        };

        loadA(z * 8); storeA(0);
        __syncthreads();

        for (int cl = 0; cl < 8; ++cl) {
            const int cg2 = z * 8 + cl;
            const int buf = cl & 1;
            if (cl + 1 < 8) loadA(cg2 + 1);

            const short* fb = wwfF + cg2 * WWF_STEP + lane * 8;
            short8 bh[7], bl[7];
            #pragma unroll
            for (int j = 0; j < 7; j++) {
                bh[j] = *(const short8*)(fb + j * 1024);
                bl[j] = *(const short8*)(fb + j * 1024 + 512);
            }
            short8 a_h = *(const short8*)&Ah[buf*2048 + (wv*16 + m16)*32 + fsw];
            short8 a_l = *(const short8*)&Al[buf*2048 + (wv*16 + m16)*32 + fsw];
            #pragma unroll
            for (int j = 0; j < 7; j++) {
                acc[j] = __builtin_amdgcn_mfma_f32_16x16x32_bf16(a_h, bh[j], acc[j], 0, 0, 0);
                acc[j] = __builtin_amdgcn_mfma_f32_16x16x32_bf16(a_h, bl[j], acc[j], 0, 0, 0);
                acc[j] = __builtin_amdgcn_mfma_f32_16x16x32_bf16(a_l, bh[j], acc[j], 0, 0, 0);
            }
            if (cl + 1 < 8) {
                storeA(buf ^ 1);
                __syncthreads();
            }
        }

        // f32 partial store (float4, disjoint per z -> deterministic)
        float* Cb = partT + (long long)z * PART_PER_Z;
        const int r = row0 + wv*16 + quad*4;          // 4-aligned, never crosses bb
        const int bb2 = r / N_WF, n = r - bb2 * N_WF;
        #pragma unroll
        for (int j = 0; j < 7; j++) {
            int cc = j * 16 + m16;
            if (cc >= WF_D) continue;
            float4 t;
            t.x = acc[j][0]; t.y = acc[j][1]; t.z = acc[j][2]; t.w = acc[j][3];
            *(float4*)&Cb[((long long)bb2 * PART_C + cc) * PART_N + n] = t;
        }
    } else {
        // ---------------- s2 ----------------
        const int id2 = b - 400;
        const int bx = id2 & 3, by = id2 >> 2;
        const int row0 = by * 64, col0 = bx * 64;
        short* Ah = smem;            // [64][32]
        short* Al = smem + 2048;

        f32x4 acc[4];
        #pragma unroll
        for (int j = 0; j < 4; j++) acc[j] = f32x4{0.f, 0.f, 0.f, 0.f};

        for (int st = 0; st < S2_NSTEP; ++st) {
            __syncthreads();
            {   // A: 64x32 from ts, split -> LDS (swizzled)
                int kk = st * 32 + ag * 8;
                const float* ap = ts + (long long)(row0 + ar) * TS_F + kk;
                float v[8];
                if (kk + 8 <= TS_F) {
                    float4 t0 = ((const float4*)ap)[0];
                    float4 t1 = ((const float4*)ap)[1];
                    v[0]=t0.x; v[1]=t0.y; v[2]=t0.z; v[3]=t0.w;
                    v[4]=t1.x; v[5]=t1.y; v[6]=t1.z; v[7]=t1.w;
                } else {
                    #pragma unroll
                    for (int q = 0; q < 8; q++) v[q] = (kk + q < TS_F) ? ap[q] : 0.f;
                }
                short8 h8, l8;
                #pragma unroll
                for (int q = 0; q < 8; q++) { short h, s; split_bf16(v[q], h, s); h8[q]=h; l8[q]=s; }
                *(short8*)&Ah[ar*32 + asw] = h8;
                *(short8*)&Al[ar*32 + asw] = l8;
            }
            __syncthreads();

            const short* fb = wtsF + st * WTS_STEP + (bx*4) * 1024 + lane * 8;
            short8 a_h = *(const short8*)&Ah[(wv*16 + m16)*32 + fsw];
            short8 a_l = *(const short8*)&Al[(wv*16 + m16)*32 + fsw];
            #pragma unroll
            for (int j = 0; j < 4; j++) {
                short8 b_h = *(const short8*)(fb + j * 1024);
                short8 b_l = *(const short8*)(fb + j * 1024 + 512);
                acc[j] = __builtin_amdgcn_mfma_f32_16x16x32_bf16(a_h, b_h, acc[j], 0, 0, 0);
                acc[j] = __builtin_amdgcn_mfma_f32_16x16x32_bf16(a_h, b_l, acc[j], 0, 0, 0);
                acc[j] = __builtin_amdgcn_mfma_f32_16x16x32_bf16(a_l, b_h, acc[j], 0, 0, 0);
            }
        }

        #pragma unroll
        for (int j = 0; j < 4; j++) {
            int fc = col0 + j * 16 + m16;           // featA fc [0,256)
            float bv = b_ts[fc];
            #pragma unroll
            for (int rr = 0; rr < 4; rr++) {
                int r = row0 + wv*16 + quad*4 + rr;
                float v = tanhf(acc[j][rr] + bv);
                short h, s; split_bf16(v, h, s);
                long long fo = fa_addr(r, fc);
                featAH[fo] = h; featAL[fo] = s;
            }
        }
    }
}

// ---- K2: reduce 4 z-slices + b_wf, split, write k3 frag layout ------------
// grid 448 = bb(32) x st(7) x half(2); block 256 = j-half(4 waves) x 64 lanes
__global__ __launch_bounds__(256)
void k2_reduce(const float* __restrict__ partT, const float* __restrict__ b_wf,
               short* __restrict__ wfo3F)
{
    const int blk = blockIdx.x, tid = threadIdx.x;
    const int bb = blk / 14, rem = blk % 14;
    const int st = rem >> 1, half = rem & 1;
    const int j = half * 4 + (tid >> 6);
    const int g = tid & 63;
    const int m16 = g & 15, kk8 = g >> 4;
    const int c = j * 16 + m16;
    const int n = st * 32 + kk8 * 8;

    float v[8];
    if (c < WF_D && n < N_WF) {
        float bw = b_wf[c];
        #pragma unroll
        for (int q = 0; q < 8; q++) v[q] = bw;
        #pragma unroll
        for (int z = 0; z < S1_Z; z++) {
            const float* p = partT + (long long)z * PART_PER_Z
                           + ((long long)bb * PART_C + c) * PART_N + n;
            float4 t0 = ((const float4*)p)[0];
            float4 t1 = ((const float4*)p)[1];
            v[0]+=t0.x; v[1]+=t0.y; v[2]+=t0.z; v[3]+=t0.w;
            v[4]+=t1.x; v[5]+=t1.y; v[6]+=t1.z; v[7]+=t1.w;
        }
    } else {
        #pragma unroll
        for (int q = 0; q < 8; q++) v[q] = 0.f;
    }
    short8 h8, l8;
    #pragma unroll
    for (int q = 0; q < 8; q++) { short h, s; split_bf16(v[q], h, s); h8[q]=h; l8[q]=s; }
    long long base = (long long)bb * WFO3_PER_B + st * (K3_NJ*1024) + j * 1024 + g * 8;
    *(short8*)(wfo3F + base)       = h8;
    *(short8*)(wfo3F + base + 512) = l8;
}

// ---- K3: featA fc[256,356) = (wwm[b] @ wf_out[b]) / 200, frag-B -----------
__global__ __launch_bounds__(256)
void k3_s3(const float* __restrict__ wwm, const short* __restrict__ wfo3F,
           short* __restrict__ featAH, short* __restrict__ featAL)
{
    __shared__ short Ah[2048], Al[2048];

    const int id = blockIdx.x, tid = threadIdx.x;
    const int wv = tid >> 6, lane = tid & 63;
    const int m16 = lane & 15, quad = lane >> 4;
    const int fsw = (quad ^ ((m16 >> 1) & 3)) * 8;
    const int ar = tid >> 2, ag = tid & 3;
    const int asw = (ag ^ ((ar >> 1) & 3)) * 8;

    const int bz = id >> 4, r4 = id & 15, bx = r4 >> 3, by = r4 & 7;
    const float* A = wwm + (long long)bz * TT * N_WF;
    const short* FB = wfo3F + (long long)bz * WFO3_PER_B;
    const int row0 = by * 64, col0 = bx * 64;

    f32x4 acc[4];
    #pragma unroll
    for (int j = 0; j < 4; j++) acc[j] = f32x4{0.f, 0.f, 0.f, 0.f};

    for (int st = 0; st < K3_NSTEP; ++st) {
        __syncthreads();
        {   // A: 64x32 from wwm
            int kk = st * 32 + ag * 8;
            const float* ap = A + (long long)(row0 + ar) * N_WF + kk;
            float v[8];
            if (kk + 8 <= N_WF) {
                float4 t0 = ((const float4*)ap)[0];
                float4 t1 = ((const float4*)ap)[1];
                v[0]=t0.x; v[1]=t0.y; v[2]=t0.z; v[3]=t0.w;
                v[4]=t1.x; v[5]=t1.y; v[6]=t1.z; v[7]=t1.w;
            } else {
                #pragma unroll
                for (int q = 0; q < 8; q++) v[q] = (kk + q < N_WF) ? ap[q] : 0.f;
            }
            short8 h8, l8;
            #pragma unroll
            for (int q = 0; q < 8; q++) { short h, s; split_bf16(v[q], h, s); h8[q]=h; l8[q]=s; }
            *(short8*)&Ah[ar*32 + asw] = h8;
            *(short8*)&Al[ar*32 + asw] = l8;
        }
        __syncthreads();

        const short* fb = FB + st * (K3_NJ*1024) + (bx*4) * 1024 + lane * 8;
        short8 a_h = *(const short8*)&Ah[(wv*16 + m16)*32 + fsw];
        short8 a_l = *(const short8*)&Al[(wv*16 + m16)*32 + fsw];
        #pragma unroll
        for (int j = 0; j < 4; j++) {
            short8 b_h = *(const short8*)(fb + j * 1024);
            short8 b_l = *(const short8*)(fb + j * 1024 + 512);
            acc[j] = __builtin_amdgcn_mfma_f32_16x16x32_bf16(a_h, b_h, acc[j], 0, 0, 0);
            acc[j] = __builtin_amdgcn_mfma_f32_16x16x32_bf16(a_h, b_l, acc[j], 0, 0, 0);
            acc[j] = __builtin_amdgcn_mfma_f32_16x16x32_bf16(a_l, b_h, acc[j], 0, 0, 0);
        }
    }

    #pragma unroll
    for (int j = 0; j < 4; j++) {
        int c = col0 + j * 16 + m16;
        if (c >= WF_D) continue;
        #pragma unroll
        for (int rr = 0; rr < 4; rr++) {
            int r = bz * TT + row0 + wv*16 + quad*4 + rr;   // B-major global row
            float v = acc[j][rr] * (1.0f / N_WF);
            short h, s; split_bf16(v, h, s);
            long long fo = fa_addr(r, 256 + c);
            featAH[fo] = h; featAL[fo] = s;
        }
    }
}

// ====== K4: s4 + head. Phase 1: texts chunks 0..6 via LDS dbuf.
//            Phase 2: feat chunks 7..18 direct featA->reg, barrier-free. ====
__global__ __launch_bounds__(512)
void k4_s4head(const float* __restrict__ texts,
               const short* __restrict__ featAH, const short* __restrict__ featAL,
               const short* __restrict__ w1F,
               const float* __restrict__ b1, const float* __restrict__ W2,
               float* __restrict__ out)
{
    __shared__ short Ah[4096], Al[4096];   // [2][64][32] each

    const int tid = threadIdx.x;
    const int wv = tid >> 6, lane = tid & 63;
    const int m16 = lane & 15, quad = lane >> 4;
    const int row0 = blockIdx.x * 64;

    const int fsw = (quad ^ ((m16 >> 1) & 3)) * 8;

    // A staging (tid < 256)
    const int ar  = tid >> 2;
    const int ag  = tid & 3;
    const int asw = (ag ^ ((ar >> 1) & 3)) * 8;
    const long long gr = row0 + ar;

    f32x4 acc[4][2];
    #pragma unroll
    for (int i = 0; i < 4; i++)
        #pragma unroll
        for (int j = 0; j < 2; j++) acc[i][j] = f32x4{0.f, 0.f, 0.f, 0.f};

    float va[8];

    auto load_chunk = [&](int c) {      // texts chunks only (c in [0,7))
        if (tid < 256) {
            int kc = c * 32 + ag * 8;
            if (kc + 8 <= TEXT_D) {     // 200%8==0: never straddles
                const float4* p = (const float4*)(texts + gr * TEXT_D + kc);
                float4 t0 = p[0], t1 = p[1];
                va[0]=t0.x; va[1]=t0.y; va[2]=t0.z; va[3]=t0.w;
                va[4]=t1.x; va[5]=t1.y; va[6]=t1.z; va[7]=t1.w;
            } else {                    // K-order zeros [200,224)
                #pragma unroll
                for (int q = 0; q < 8; q++) va[q] = 0.f;
            }
        }
    };
    auto store_chunk = [&](int buf) {
        if (tid < 256) {
            short8 h8, l8;
            #pragma unroll
            for (int q = 0; q < 8; q++) { short h, s; split_bf16(va[q], h, s); h8[q]=h; l8[q]=s; }
            *(short8*)&Ah[buf*2048 + ar*32 + asw] = h8;
            *(short8*)&Al[buf*2048 + ar*32 + asw] = l8;
        }
    };

    // ---------- Phase 1: texts chunks 0..6 ----------
    load_chunk(0);
    store_chunk(0);
    __syncthreads();

    for (int c = 0; c < 7; c++) {
        const int buf = c & 1;
        if (c < 6) load_chunk(c + 1);

        short8 a_h[4], a_l[4];
        #pragma unroll
        for (int ri = 0; ri < 4; ri++) {
            a_h[ri] = *(const short8*)&Ah[buf*2048 + (ri*16 + m16)*32 + fsw];
            a_l[ri] = *(const short8*)&Al[buf*2048 + (ri*16 + m16)*32 + fsw];
        }
        #pragma unroll
        for (int ci = 0; ci < 2; ci++) {
            int jj = wv * 2 + ci;
            const short* fb = w1F + (c * 16 + jj) * 1024 + lane * 8;
            short8 b_h = *(const short8*)fb;
            short8 b_l = *(const short8*)(fb + 512);
            #pragma unroll
            for (int ri = 0; ri < 4; ri++) {
                acc[ri][ci] = __builtin_amdgcn_mfma_f32_16x16x32_bf16(a_h[ri], b_h, acc[ri][ci], 0, 0, 0);
                acc[ri][ci] = __builtin_amdgcn_mfma_f32_16x16x32_bf16(a_h[ri], b_l, acc[ri][ci], 0, 0, 0);
                acc[ri][ci] = __builtin_amdgcn_mfma_f32_16x16x32_bf16(a_l[ri], b_h, acc[ri][ci], 0, 0, 0);
            }
        }
        if (c < 6) {
            store_chunk(buf ^ 1);
            __syncthreads();
        }
    }

    // ---------- Phase 2: feat chunks 7..18, barrier-free, P/Q pipeline ----
    short8 pah[4], pal[4], qah[4], qal[4];
    short8 pbh[2], pbl[2], qbh[2], qbl[2];

    auto loadP = [&](int c) {
        long long base = (((long long)blockIdx.x * 12 + (c - 7)) << 11) + lane * 8;
        #pragma unroll
        for (int ri = 0; ri < 4; ri++) {
            pah[ri] = *(const short8*)(featAH + base + ri * 512);
            pal[ri] = *(const short8*)(featAL + base + ri * 512);
        }
        #pragma unroll
        for (int ci = 0; ci < 2; ci++) {
            const short* fb = w1F + (c * 16 + wv * 2 + ci) * 1024 + lane * 8;
            pbh[ci] = *(const short8*)fb;
            pbl[ci] = *(const short8*)(fb + 512);
        }
    };
    auto loadQ = [&](int c) {
        long long base = (((long long)blockIdx.x * 12 + (c - 7)) << 11) + lane * 8;
        #pragma unroll
        for (int ri = 0; ri < 4; ri++) {
            qah[ri] = *(const short8*)(featAH + base + ri * 512);
            qal[ri] = *(const short8*)(featAL + base + ri * 512);
        }
        #pragma unroll
        for (int ci = 0; ci < 2; ci++) {
            const short* fb = w1F + (c * 16 + wv * 2 + ci) * 1024 + lane * 8;
            qbh[ci] = *(const short8*)fb;
            qbl[ci] = *(const short8*)(fb + 512);
        }
    };
    auto mfmaP = [&]() {
        #pragma unroll
        for (int ci = 0; ci < 2; ci++)
            #pragma unroll
            for (int ri = 0; ri < 4; ri++) {
                acc[ri][ci] = __builtin_amdgcn_mfma_f32_16x16x32_bf16(pah[ri], pbh[ci], acc[ri][ci], 0, 0, 0);
                acc[ri][ci] = __builtin_amdgcn_mfma_f32_16x16x32_bf16(pah[ri], pbl[ci], acc[ri][ci], 0, 0, 0);
                acc[ri][ci] = __builtin_amdgcn_mfma_f32_16x16x32_bf16(pal[ri], pbh[ci], acc[ri][ci], 0, 0, 0);
            }
    };
    auto mfmaQ = [&]() {
        #pragma unroll
        for (int ci = 0; ci < 2; ci++)
            #pragma unroll
            for (int ri = 0; ri < 4; ri++) {
                acc[ri][ci] = __builtin_amdgcn_mfma_f32_16x16x32_bf16(qah[ri], qbh[ci], acc[ri][ci], 0, 0, 0);
                acc[ri][ci] = __builtin_amdgcn_mfma_f32_16x16x32_bf16(qah[ri], qbl[ci], acc[ri][ci], 0, 0, 0);
                acc[ri][ci] = __builtin_amdgcn_mfma_f32_16x16x32_bf16(qal[ri], qbh[ci], acc[ri][ci], 0, 0, 0);
            }
    };

    loadP(7);
    #pragma unroll
    for (int c = 7; c < 19; c += 2) {
        loadQ(c + 1);                 // c+1 <= 18 always (12 chunks, even)
        mfmaP();
        if (c + 2 < 19) loadP(c + 2);
        mfmaQ();
    }

    // epilogue: relu + fused head over this wave's 32 cols
    float o0[4][4] = {}, o1[4][4] = {};
    #pragma unroll
    for (int ci = 0; ci < 2; ci++) {
        int C = wv * 32 + ci * 16 + m16;
        float bv  = b1[C];
        float w20 = W2[C * 2 + 0];
        float w21 = W2[C * 2 + 1];
        #pragma unroll
        for (int ri = 0; ri < 4; ri++)
            #pragma unroll
            for (int rr = 0; rr < 4; rr++) {
                float v = fmaxf(acc[ri][ci][rr] + bv, 0.f);
                o0[ri][rr] += v * w20;
                o1[ri][rr] += v * w21;
            }
    }
    #pragma unroll
    for (int ri = 0; ri < 4; ri++)
        #pragma unroll
        for (int rr = 0; rr < 4; rr++) {
            float s0 = o0[ri][rr], s1 = o1[ri][rr];
            #pragma unroll
            for (int mk = 1; mk < 16; mk <<= 1) {
                s0 += __shfl_xor(s0, mk);
                s1 += __shfl_xor(s1, mk);
            }
            if (m16 == 0) {
                int r = row0 + ri * 16 + quad * 4 + rr;
                atomicAdd(&out[r * 2 + 0], s0);
                atomicAdd(&out[r * 2 + 1], s1);
            }
        }
}

extern "C" void kernel_launch(void* const* d_in, const int* in_sizes, int n_in,
                              void* d_out, int out_size, void* d_ws, size_t ws_size,
                              hipStream_t stream)
{
    const float* texts = (const float*)d_in[0];   // (512,32,200)
    const float* ts    = (const float*)d_in[1];   // (512,32,76)
    const float* wf    = (const float*)d_in[2];   // (32,200,1000)
    const float* wwm   = (const float*)d_in[3];   // (32,512,200)
    const float* W_wf  = (const float*)d_in[4];   // (1000,100)
    const float* b_wf  = (const float*)d_in[5];
    const float* W_ts  = (const float*)d_in[6];   // (76,256)
    const float* b_ts  = (const float*)d_in[7];
    const float* W1    = (const float*)d_in[8];   // (556,256)
    const float* b1    = (const float*)d_in[9];
    const float* W2    = (const float*)d_in[10];  // (256,2)
    const float* b2    = (const float*)d_in[11];
    float* out = (float*)d_out;

    // ---- workspace layout (all disjoint, ~43 MB) ----
    float* partT  = (float*)d_ws;                      // 4*802816 f32
    short* wwfF   = (short*)(partT + S1_Z * PART_PER_Z);
    short* wtsF   = wwfF + WWF_TOT;
    short* w1F    = wtsF + WTS_TOT;
    short* wfo3F  = w1F + W1F_TOT;
    short* featAH = wfo3F + WFO3_TOT;                  // frag-layout feat planes
    short* featAL = featAH + FA_TOT;

    // 0) one-time: B fragment packs + out init + featA zero region
    k0_prep<<<336, 256, 0, stream>>>(W_wf, W_ts, W1, b2,
                                     wwfF, wtsF, w1F, out, featAH, featAL);

    // 1) s1 split-K partials + s2 (featA fc[0,256))
    k1_main<<<1424, 256, 0, stream>>>(wf, ts, b_ts, wwfF, wtsF,
                                      partT, featAH, featAL);

    // 2) reduce z-slices + b_wf -> wf_out^T frag layout
    k2_reduce<<<448, 256, 0, stream>>>(partT, b_wf, wfo3F);

    // 3) s3 spread cols -> featA fc[256,356)
    k3_s3<<<512, 256, 0, stream>>>(wwm, wfo3F, featAH, featAL);

    // 4) s4 + head
    k4_s4head<<<ROWS / 64, 512, 0, stream>>>(texts, featAH, featAL,
                                             w1F, b1, W2, out);
}